// Round 7
// baseline (640.066 us; speedup 1.0000x reference)
//
#include <hip/hip_runtime.h>

// LAPACK slartg vintage: 1 = LAPACK >= 3.10
#define SLARTG_NEW 1

namespace {

constexpr int KNN_K = 5;
constexpr int PPB = 64;              // points per block
constexpr int STR = 4;               // j-stripes per point
constexpr int TPB = PPB * STR;       // 256 threads
constexpr int TILE = 2048;           // points staged in LDS per tile

// fp32 LAPACK machine constants (exact IEEE-single values)
#define EPSF    5.9604644775390625e-8f    /* 2^-24, slamch('E') */
#define EPS2F   3.552713678800501e-15f    /* 2^-48 */
#define SAFMINF 1.1754943508222875e-38f   /* 2^-126, slamch('S') */
#define SAFMAXF 8.507059173023462e+37f    /* 2^126 */
#define RTMINF  1.0842021724855044e-19f   /* 2^-63 */
#define RTMAXF  9.223372036854776e+18f    /* 2^63 */

// ---- fp32 helpers: ALL-PLAIN rounding (no-FMA reference stack) ----
__device__ __forceinline__ float sqnorm3(float x, float y, float z) {
#pragma clang fp contract(off)
  float a = x * x;
  float b = y * y;
  float c = z * z;
  return (a + b) + c; // sequential reduce, no FMA
}

__device__ __forceinline__ float dist2(float xi, float yi, float zi, float sqi,
                                       float xj, float yj, float zj, float sqj) {
#pragma clang fp contract(off)
  float dot = (xi * xj + yi * yj) + zi * zj; // PLAIN mul+add, k ascending (no FMA)
  float a = sqi + sqj;
  return a - 2.0f * dot; // (sq_i+sq_j) - 2*dot
}

// ---- fp32 LAPACK ports (reference netlib, plain rounding) ----
__device__ __forceinline__ float slapy2f(float x, float y) {
#pragma clang fp contract(off)
  float xa = fabsf(x), ya = fabsf(y);
  float w = fmaxf(xa, ya);
  float z = fminf(xa, ya);
  if (z == 0.f) return w;
  float q = z / w;
  float q2 = q * q;
  float s = 1.0f + q2;
  return w * sqrtf(s);
}

__device__ void slartgf(float f, float g, float* cs, float* sn, float* r) {
#pragma clang fp contract(off)
#if SLARTG_NEW
  float f1 = fabsf(f), g1 = fabsf(g);
  if (g == 0.f) { *cs = 1.f; *sn = 0.f; *r = f; }
  else if (f == 0.f) { *cs = 0.f; *sn = copysignf(1.f, g); *r = g1; }
  else if (f1 > RTMINF && f1 < RTMAXF && g1 > RTMINF && g1 < RTMAXF) {
    float ff = f * f;
    float gg = g * g;
    float d = sqrtf(ff + gg);
    *cs = f1 / d;
    float rr = copysignf(d, f);
    *sn = g / rr;
    *r = rr;
  } else {
    float u = fminf(SAFMAXF, fmaxf(fmaxf(SAFMINF, f1), g1));
    float fs = f / u, gs = g / u;
    float ff = fs * fs;
    float gg = gs * gs;
    float d = sqrtf(ff + gg);
    *cs = fabsf(fs) / d;
    float rr = copysignf(d, f);
    *sn = gs / rr;
    *r = rr * u;
  }
#else
  if (g == 0.f) { *cs = 1.f; *sn = 0.f; *r = f; }
  else if (f == 0.f) { *cs = 0.f; *sn = 1.f; *r = g; }
  else {
    float f2 = f * f;
    float g2 = g * g;
    float rr = sqrtf(f2 + g2);
    float c = f / rr, s = g / rr;
    if (fabsf(f) > fabsf(g) && c < 0.f) { c = -c; s = -s; rr = -rr; }
    *cs = c; *sn = s; *r = rr;
  }
#endif
}

__device__ void slaev2f(float a, float b, float c,
                        float* rt1, float* rt2, float* cs1, float* sn1) {
#pragma clang fp contract(off)
  float sm = a + c;
  float df = a - c;
  float adf = fabsf(df);
  float tb = b + b;
  float ab = fabsf(tb);
  float acmx, acmn;
  if (fabsf(a) > fabsf(c)) { acmx = a; acmn = c; } else { acmx = c; acmn = a; }
  float rt;
  if (adf > ab) { float q = ab / adf; rt = adf * sqrtf(1.0f + q * q); }
  else if (adf < ab) { float q = adf / ab; rt = ab * sqrtf(1.0f + q * q); }
  else rt = ab * sqrtf(2.0f);
  int sgn1;
  if (sm < 0.f) { *rt1 = 0.5f * (sm - rt); sgn1 = -1; *rt2 = (acmx / *rt1) * acmn - (b / *rt1) * b; }
  else if (sm > 0.f) { *rt1 = 0.5f * (sm + rt); sgn1 = 1; *rt2 = (acmx / *rt1) * acmn - (b / *rt1) * b; }
  else { *rt1 = 0.5f * rt; *rt2 = -0.5f * rt; sgn1 = 1; }
  float cs; int sgn2;
  if (df >= 0.f) { cs = df + rt; sgn2 = 1; } else { cs = df - rt; sgn2 = -1; }
  float acs = fabsf(cs);
  float c1, s1;
  if (acs > ab) {
    float ct = -tb / cs;
    s1 = 1.0f / sqrtf(1.0f + ct * ct);
    c1 = ct * s1;
  } else {
    if (ab == 0.f) { c1 = 1.f; s1 = 0.f; }
    else {
      float tn = -cs / tb;
      c1 = 1.0f / sqrtf(1.0f + tn * tn);
      s1 = tn * c1;
    }
  }
  if (sgn1 == sgn2) { float tn = c1; c1 = -s1; s1 = tn; }
  *cs1 = c1; *sn1 = s1;
}

// SLASCL('G',...) faithful port, fp32
__device__ void slascl_g(float cfrom, float cto, int n, float* a) {
#pragma clang fp contract(off)
  float cfromc = cfrom, ctoc = cto;
  bool done = false;
  int guard = 0;
  while (!done && guard++ < 50) {
    float mul;
    float cfrom1 = cfromc * SAFMINF;
    if (cfrom1 == cfromc) {
      mul = ctoc / cfromc; done = true;
    } else {
      float cto1 = ctoc / SAFMAXF;
      if (cto1 == ctoc) { mul = ctoc; done = true; cfromc = 1.f; }
      else if (fabsf(cfrom1) > fabsf(ctoc) && ctoc != 0.f) { mul = SAFMINF; done = false; cfromc = cfrom1; }
      else if (fabsf(cto1) > fabsf(cfromc)) { mul = SAFMAXF; done = false; ctoc = cto1; }
      else { mul = ctoc / cfromc; done = true; }
    }
    for (int i = 0; i < n; ++i) a[i] = a[i] * mul;
  }
}

// Faithful fp32 port of SSTEQR('I', 3, ...) — 1-based Fortran indices via [idx-1].
__device__ void steqr3f(float* d, float* e, float Z[3][3]) {
#pragma clang fp contract(off)
  const int n = 3;
  const float eps = EPSF, eps2 = EPS2F, safmin = SAFMINF;
  const float ssfmax = sqrtf(SAFMAXF) / 3.0f;   // 2^63/3
  const float ssfmin = sqrtf(SAFMINF) / EPS2F;  // 2^-15 exact
  int jtot = 0; const int nmaxit = n * 30;
  int l1 = 1;

  for (int guard = 0; guard < 200; ++guard) {
    if (l1 > n) break;
    if (l1 > 1) e[l1 - 2] = 0.f;
    int m = n;
    if (l1 <= n - 1) {
      for (int q = l1; q <= n - 1; ++q) {
        float tst = fabsf(e[q - 1]);
        if (tst == 0.f) { m = q; break; }
        if (tst <= (sqrtf(fabsf(d[q - 1])) * sqrtf(fabsf(d[q]))) * eps) { e[q - 1] = 0.f; m = q; break; }
      }
    }
    int l = l1, lsv = l, lend = m, lendsv = lend;
    l1 = m + 1;
    if (lend == l) continue;
    // anorm = slanst('M') over segment
    float anorm = 0.f;
    for (int q = l; q <= lend; ++q) anorm = fmaxf(anorm, fabsf(d[q - 1]));
    for (int q = l; q <= lend - 1; ++q) anorm = fmaxf(anorm, fabsf(e[q - 1]));
    int iscale = 0;
    if (anorm == 0.f) continue;
    if (anorm > ssfmax) {
      iscale = 1;
      slascl_g(anorm, ssfmax, lend - l + 1, d + l - 1);
      slascl_g(anorm, ssfmax, lend - l, e + l - 1);
    } else if (anorm < ssfmin) {
      iscale = 2;
      slascl_g(anorm, ssfmin, lend - l + 1, d + l - 1);
      slascl_g(anorm, ssfmin, lend - l, e + l - 1);
    }
    if (fabsf(d[lend - 1]) < fabsf(d[l - 1])) { lend = lsv; l = lendsv; }

    if (lend > l) {
      // ================= QL =================
      for (int g2 = 0; g2 < 400; ++g2) {
        int mm = lend;
        if (l != lend) {
          bool fnd = false;
          for (int q = l; q <= lend - 1; ++q) {
            float tst = e[q - 1] * e[q - 1];
            if (tst <= (eps2 * fabsf(d[q - 1])) * fabsf(d[q]) + safmin) { mm = q; fnd = true; break; }
          }
          if (!fnd) mm = lend;
        }
        if (mm < lend) e[mm - 1] = 0.f;
        float p = d[l - 1];
        if (mm == l) {
          d[l - 1] = p; ++l;
          if (l <= lend) continue; else break;
        }
        if (mm == l + 1) {
          float rt1, rt2, c, s;
          slaev2f(d[l - 1], e[l - 1], d[l], &rt1, &rt2, &c, &s);
          // SLASR 'R','V','B' on Fortran cols (l, l+1)
          for (int r2 = 0; r2 < 3; ++r2) {
            float zt = Z[r2][l];       // Fortran col l+1
            float zl = Z[r2][l - 1];   // Fortran col l
            Z[r2][l] = c * zt - s * zl;
            Z[r2][l - 1] = s * zt + c * zl;
          }
          d[l - 1] = rt1; d[l] = rt2; e[l - 1] = 0.f;
          l += 2;
          if (l <= lend) continue; else break;
        }
        if (jtot == nmaxit) break;
        ++jtot;
        float g = (d[l] - p) / (2.0f * e[l - 1]);
        float r = slapy2f(g, 1.0f);
        g = d[mm - 1] - p + e[l - 1] / (g + copysignf(r, g));
        float ss = 1.0f, cc = 1.0f;
        p = 0.f;
        float cw[2], sw[2];
        for (int q = mm - 1; q >= l; --q) {
          float f = ss * e[q - 1];
          float b = cc * e[q - 1];
          float rr;
          slartgf(g, f, &cc, &ss, &rr);
          if (q != mm - 1) e[q] = rr;
          g = d[q] - p;
          rr = (d[q - 1] - g) * ss + 2.0f * cc * b;
          p = ss * rr;
          d[q] = g + p;
          g = cc * rr - b;
          cw[q - l] = cc; sw[q - l] = -ss;  // WORK(i)=c, WORK(n-1+i)=-s
        }
        // SLASR 'R','V','B': j = mm-1 .. l descending
        for (int q = mm - 1; q >= l; --q) {
          float cj = cw[q - l], sj = sw[q - l];
          for (int r2 = 0; r2 < 3; ++r2) {
            float zt = Z[r2][q];
            float zl = Z[r2][q - 1];
            Z[r2][q] = cj * zt - sj * zl;
            Z[r2][q - 1] = sj * zt + cj * zl;
          }
        }
        d[l - 1] = d[l - 1] - p;
        e[l - 1] = g;
      }
    } else {
      // ================= QR =================
      for (int g2 = 0; g2 < 400; ++g2) {
        int mm = lend;
        if (l != lend) {
          bool fnd = false;
          for (int q = l; q >= lend + 1; --q) {
            float tst = e[q - 2] * e[q - 2];
            if (tst <= (eps2 * fabsf(d[q - 1])) * fabsf(d[q - 2]) + safmin) { mm = q; fnd = true; break; }
          }
          if (!fnd) mm = lend;
        }
        if (mm > lend) e[mm - 2] = 0.f;
        float p = d[l - 1];
        if (mm == l) {
          d[l - 1] = p; --l;
          if (l >= lend) continue; else break;
        }
        if (mm == l - 1) {
          float rt1, rt2, c, s;
          slaev2f(d[l - 2], e[l - 2], d[l - 1], &rt1, &rt2, &c, &s);
          // SLASR 'R','V','F' on Fortran cols (l-1, l)
          for (int r2 = 0; r2 < 3; ++r2) {
            float zt = Z[r2][l - 1];   // Fortran col l
            float zl = Z[r2][l - 2];   // Fortran col l-1
            Z[r2][l - 1] = c * zt - s * zl;
            Z[r2][l - 2] = s * zt + c * zl;
          }
          d[l - 2] = rt1; d[l - 1] = rt2; e[l - 2] = 0.f;
          l -= 2;
          if (l >= lend) continue; else break;
        }
        if (jtot == nmaxit) break;
        ++jtot;
        float g = (d[l - 2] - p) / (2.0f * e[l - 2]);
        float r = slapy2f(g, 1.0f);
        g = d[mm - 1] - p + e[l - 2] / (g + copysignf(r, g));
        float ss = 1.0f, cc = 1.0f;
        p = 0.f;
        float cw[2], sw[2];
        for (int q = mm; q <= l - 1; ++q) {
          float f = ss * e[q - 1];
          float b = cc * e[q - 1];
          float rr;
          slartgf(g, f, &cc, &ss, &rr);
          if (q != mm) e[q - 2] = rr;
          g = d[q - 1] - p;
          rr = (d[q] - g) * ss + 2.0f * cc * b;
          p = ss * rr;
          d[q - 1] = g + p;
          g = cc * rr - b;
          cw[q - mm] = cc; sw[q - mm] = ss;  // WORK(i)=c, WORK(n-1+i)=+s
        }
        // SLASR 'R','V','F': j = mm .. l-1 ascending
        for (int q = mm; q <= l - 1; ++q) {
          float cj = cw[q - mm], sj = sw[q - mm];
          for (int r2 = 0; r2 < 3; ++r2) {
            float zt = Z[r2][q];
            float zl = Z[r2][q - 1];
            Z[r2][q] = cj * zt - sj * zl;
            Z[r2][q - 1] = sj * zt + cj * zl;
          }
        }
        d[l - 1] = d[l - 1] - p;
        e[l - 2] = g;
      }
    }
    // label 140: undo scaling on the whole original segment
    if (iscale == 1) {
      slascl_g(ssfmax, anorm, lendsv - lsv + 1, d + lsv - 1);
      slascl_g(ssfmax, anorm, lendsv - lsv, e + lsv - 1);
    } else if (iscale == 2) {
      slascl_g(ssfmin, anorm, lendsv - lsv + 1, d + lsv - 1);
      slascl_g(ssfmin, anorm, lendsv - lsv, e + lsv - 1);
    }
    if (jtot >= nmaxit) break;
  }
  // Final: selection sort ascending, swapping eigenvector columns (as in SSTEQR)
  for (int ii = 2; ii <= n; ++ii) {
    int i0 = ii - 1, k0 = i0;
    float p = d[i0 - 1];
    for (int j = ii; j <= n; ++j)
      if (d[j - 1] < p) { k0 = j; p = d[j - 1]; }
    if (k0 != i0) {
      d[k0 - 1] = d[i0 - 1]; d[i0 - 1] = p;
      for (int r2 = 0; r2 < 3; ++r2) {
        float t = Z[r2][i0 - 1]; Z[r2][i0 - 1] = Z[r2][k0 - 1]; Z[r2][k0 - 1] = t;
      }
    }
  }
}

__device__ __forceinline__ float vote5(const float dif[KNN_K][3],
                                       float px, float py, float pz, const float v[3]) {
#pragma clang fp contract(off)
  int cnt = 0;
  for (int k = 0; k < KNN_K; ++k) {
    float w0 = dif[k][0] - px;
    float w1 = dif[k][1] - py;
    float w2 = dif[k][2] - pz;
    float dt = (w0 * v[0] + w1 * v[1]) + w2 * v[2]; // plain, no FMA
    cnt += (dt >= -1e-5f) ? 1 : 0;
  }
  return (2 * cnt >= KNN_K) ? 1.0f : -1.0f;
}

__device__ void lrf_one(const float* __restrict__ P, float* __restrict__ out,
                        int i, const int* nb) {
#pragma clang fp contract(off)
  float px = P[i * 3 + 0], py = P[i * 3 + 1], pz = P[i * 3 + 2];
  float dif[KNN_K][3];
  for (int k = 0; k < KNN_K; ++k) {
    int j = nb[k];
    dif[k][0] = P[j * 3 + 0] - px;
    dif[k][1] = P[j * 3 + 1] - py;
    dif[k][2] = P[j * 3 + 2] - pz;
  }
  float mean[3];
  for (int c = 0; c < 3; ++c) {
    float sm = dif[0][c];
    for (int k = 1; k < KNN_K; ++k) sm = sm + dif[k][c];
    mean[c] = sm / 5.0f;
  }
  float cen[KNN_K][3];
  for (int k = 0; k < KNN_K; ++k)
    for (int c = 0; c < 3; ++c) cen[k][c] = dif[k][c] - mean[c];
  float cov[3][3];
  for (int a = 0; a < 3; ++a)
    for (int b = 0; b < 3; ++b) {
      float sm = cen[0][a] * cen[0][b];  // plain mul+add ascending, no FMA
      for (int k = 1; k < KNN_K; ++k) sm = sm + cen[k][a] * cen[k][b];
      cov[a][b] = sm / 5.0f;
    }

  // ---- SSYTD2('L', 3) exact fp32, plain reference-BLAS rounding ----
  float a00 = cov[0][0], a10 = cov[1][0], a20 = cov[2][0];
  float a11 = cov[1][1], a21 = cov[2][1], a22 = cov[2][2];
  float dd[3], ee[2];
  float taui = 0.f, v2 = 0.f;
  float xnorm = fabsf(a20);
  if (xnorm == 0.f) {
    taui = 0.f;
    ee[0] = a10;
    dd[0] = a00; dd[1] = a11; dd[2] = a22; ee[1] = a21;
  } else {
    float beta = -copysignf(slapy2f(a10, xnorm), a10);
    taui = (beta - a10) / beta;
    v2 = a20 * (1.0f / (a10 - beta));      // SSCAL: reciprocal then multiply
    ee[0] = beta;
    // SSYMV('L',2,taui,A2,v=(1,v2),0,w) reference order:
    float w1 = taui * a11 + taui * (a21 * v2);
    float w2 = taui * a21 + (taui * v2) * a22;
    // alpha = -0.5*taui*sdot(w,v); sdot = w1 + w2*v2
    float dot = w1 + w2 * v2;
    float al = -((0.5f * taui) * dot);
    // SAXPY: w += al*v
    w1 = w1 + al;
    w2 = w2 + al * v2;
    // SSYR2('L',2,-1,v,w,A2): A(i,j) = (A(i,j) + x(i)*(-w_j)) + y(i)*(-v_j)
    dd[1] = (a11 - w1) - w1;
    ee[1] = (a21 - (v2 * w1)) - w2;
    dd[2] = (a22 - (v2 * w2)) - (w2 * v2);
    dd[0] = a00;
  }

  float Zm[3][3] = {{1.f, 0.f, 0.f}, {0.f, 1.f, 0.f}, {0.f, 0.f, 1.f}};
  steqr3f(dd, ee, Zm);

  // ---- SORMTR/SLARF: Z := H(1)*Z, H = I - tau*u*u^T, u=(0,1,v2); plain sgemv+sger ----
  if (taui != 0.f) {
    for (int j = 0; j < 3; ++j) {
      float w = Zm[1][j] + v2 * Zm[2][j];   // sgemv 'T', plain
      float t = -(taui * w);                // sger temp = (-tau)*w
      Zm[1][j] = Zm[1][j] + t;
      Zm[2][j] = Zm[2][j] + v2 * t;
    }
  }

  // order = [2,1,0] always (eigvals ascending) -> x_axis = ROW 2, z_axis = ROW 0
  float vx[3] = {Zm[2][0], Zm[2][1], Zm[2][2]};
  float vz[3] = {Zm[0][0], Zm[0][1], Zm[0][2]};
  float sx = vote5(dif, px, py, pz, vx);
  float sz = vote5(dif, px, py, pz, vz);
  float X[3] = {vx[0] * sx, vx[1] * sx, vx[2] * sx};
  float Zx[3] = {vz[0] * sz, vz[1] * sz, vz[2] * sz};
  float Y[3] = {Zx[1] * X[2] - Zx[2] * X[1],
                Zx[2] * X[0] - Zx[0] * X[2],
                Zx[0] * X[1] - Zx[1] * X[0]};
  out[i * 9 + 0] = X[0]; out[i * 9 + 1] = X[1]; out[i * 9 + 2] = X[2];
  out[i * 9 + 3] = Y[0]; out[i * 9 + 4] = Y[1]; out[i * 9 + 5] = Y[2];
  out[i * 9 + 6] = Zx[0]; out[i * 9 + 7] = Zx[1]; out[i * 9 + 8] = Zx[2];
}

__global__ __launch_bounds__(TPB) void SHOTDescriptor_64622077935970_kernel(
    const float* __restrict__ P, float* __restrict__ out, int n) {
  __shared__ float4 tile[TILE];
  __shared__ float md[PPB][STR][KNN_K];
  __shared__ int mi[PPB][STR][KNN_K];
  __shared__ int nidx[PPB][KNN_K];

  const int tid = threadIdx.x;
  const int p = tid >> 2;
  const int s = tid & 3;
  const int i = blockIdx.x * PPB + p;

  float pix = 0.f, piy = 0.f, piz = 0.f, sqi = 0.f;
  if (i < n) {
    pix = P[i * 3 + 0]; piy = P[i * 3 + 1]; piz = P[i * 3 + 2];
    sqi = sqnorm3(pix, piy, piz);
  }
  float bd[KNN_K]; int bi[KNN_K];
  for (int k = 0; k < KNN_K; ++k) { bd[k] = 1e30f; bi[k] = 0x7fffffff; }

  for (int base = 0; base < n; base += TILE) {
    int cnt = min(TILE, n - base);
    __syncthreads();
    for (int j = tid; j < cnt; j += TPB) {
      float x = P[(base + j) * 3 + 0];
      float y = P[(base + j) * 3 + 1];
      float z = P[(base + j) * 3 + 2];
      tile[j] = make_float4(x, y, z, sqnorm3(x, y, z));
    }
    __syncthreads();
    if (i < n) {
      for (int j = s; j < cnt; j += STR) {
        float4 q = tile[j];
        float dd = dist2(pix, piy, piz, sqi, q.x, q.y, q.z, q.w);
        if (dd < bd[KNN_K - 1]) {
          int gj = base + j;
          int pos = KNN_K - 1;
          while (pos > 0 && dd < bd[pos - 1]) {
            bd[pos] = bd[pos - 1]; bi[pos] = bi[pos - 1]; --pos;
          }
          bd[pos] = dd; bi[pos] = gj;
        }
      }
    }
  }
  for (int k = 0; k < KNN_K; ++k) { md[p][s][k] = bd[k]; mi[p][s][k] = bi[k]; }
  __syncthreads();

  if (s == 0 && i < n) {
    // merge 4 partial top-5 lists -> global top-5, total order (d2, idx) = top_k semantics
    float cd[STR * KNN_K]; int ci[STR * KNN_K]; bool used[STR * KNN_K];
    for (int a = 0; a < STR; ++a)
      for (int k = 0; k < KNN_K; ++k) {
        cd[a * KNN_K + k] = md[p][a][k];
        ci[a * KNN_K + k] = mi[p][a][k];
        used[a * KNN_K + k] = false;
      }
    for (int r = 0; r < KNN_K; ++r) {
      int best = -1;
      for (int a = 0; a < STR * KNN_K; ++a) {
        if (used[a]) continue;
        if (best < 0 || cd[a] < cd[best] || (cd[a] == cd[best] && ci[a] < ci[best]))
          best = a;
      }
      used[best] = true;
      nidx[p][r] = ci[best];
    }
  }
  __syncthreads();

  if (tid < PPB) {
    int ii = blockIdx.x * PPB + tid;
    if (ii < n) lrf_one(P, out, ii, nidx[tid]);
  }
}

}  // namespace

extern "C" void kernel_launch(void* const* d_in, const int* in_sizes, int n_in,
                              void* d_out, int out_size, void* d_ws, size_t ws_size,
                              hipStream_t stream) {
  (void)n_in; (void)d_ws; (void)ws_size; (void)out_size;
  const float* P = (const float*)d_in[0];
  float* out = (float*)d_out;
  const int n = in_sizes[0] / 3;
  if (n <= 0) return;
  const int blocks = (n + PPB - 1) / PPB;
  SHOTDescriptor_64622077935970_kernel<<<blocks, TPB, 0, stream>>>(P, out, n);
}